// Round 3
// baseline (401.479 us; speedup 1.0000x reference)
//
#include <hip/hip_runtime.h>
#include <hip/hip_bf16.h>
#include <math.h>

#define B_ 64
#define S_ 512
#define VEC_ 768
#define H_ 256
#define M_ (B_*S_)   // 32768

typedef float floatx4 __attribute__((ext_vector_type(4)));
typedef __bf16 bf16x8 __attribute__((ext_vector_type(8)));
typedef __bf16 bf16x4 __attribute__((ext_vector_type(4)));

// prep: cast mlp_w (f32 [256,768]) -> bf16, zero doc-sum accumulators
__global__ __launch_bounds__(256) void prep_kernel(
    const float* __restrict__ mlp_w, __bf16* __restrict__ wbf, float* __restrict__ sums)
{
  const int bid = blockIdx.x;
  if (bid < 192) {
    const int i = bid * 256 + threadIdx.x;           // float4 index, 49152 total
    const float4 v = ((const float4*)mlp_w)[i];
    bf16x4 b = { (__bf16)v.x, (__bf16)v.y, (__bf16)v.z, (__bf16)v.w };
    *(bf16x4*)&wbf[(size_t)i * 4] = b;
  } else {
    const int i = (bid - 192) * 256 + threadIdx.x;   // 8192 float4 = 2*64*256 f32
    ((float4*)sums)[i] = make_float4(0.f, 0.f, 0.f, 0.f);
  }
}

// Barrier-free MFMA GEMM: C[m,n] = relu(sum_k A[m,k]*W[n,k] + mlp_b[n]).
// No LDS, no __syncthreads: each lane loads its MFMA fragment directly from
// global (A/W are K-contiguous and the 16x16x32 operand layout wants 16
// contiguous bytes per lane at k = quad*8). Loads pipeline via fine-grained
// vmcnt across the fully unrolled K-loop — no barrier vmcnt(0) drains.
__global__ __launch_bounds__(256, 2) void gemm_doc_kernel(
    const float* __restrict__ out1, const float* __restrict__ out2,
    const __bf16* __restrict__ wbf, const float* __restrict__ mlp_b,
    __bf16* __restrict__ o1, float* __restrict__ sum1, float* __restrict__ sum2)
{
  const int tensor = blockIdx.z;
  const float* __restrict__ A = tensor ? out2 : out1;
  float* __restrict__ dsum = tensor ? sum2 : sum1;

  const int n0 = blockIdx.x * 128;
  const int m0 = blockIdx.y * 128;
  const int bidx = m0 >> 9;  // 512 rows per doc; m-tiles never straddle docs

  const int lane = threadIdx.x & 63;
  const int wave = threadIdx.x >> 6;
  const int q = lane >> 4;      // k-quad: fragment k-offset = q*8
  const int c = lane & 15;      // m (A) / n (B) index within 16
  const int wm = (wave >> 1) * 64;
  const int wn = (wave & 1) * 64;

  // per-lane fragment base pointers (k advances by +=32)
  const float* Ab[4];
  const __bf16* Bb[4];
#pragma unroll
  for (int i = 0; i < 4; i++)
    Ab[i] = A + (size_t)(m0 + wm + i * 16 + c) * VEC_ + q * 8;
#pragma unroll
  for (int j = 0; j < 4; j++)
    Bb[j] = wbf + (size_t)(n0 + wn + j * 16 + c) * VEC_ + q * 8;

  floatx4 acc[4][4];
#pragma unroll
  for (int i = 0; i < 4; i++)
#pragma unroll
    for (int j = 0; j < 4; j++)
      acc[i][j] = (floatx4){0.f, 0.f, 0.f, 0.f};

  float4 a0[4], a1[4], na0[4], na1[4];
  bf16x8 b0[4], nb0[4];

  // prologue: fragments for k0 = 0
#pragma unroll
  for (int i = 0; i < 4; i++) { a0[i] = *(const float4*)Ab[i]; a1[i] = *(const float4*)(Ab[i] + 4); }
#pragma unroll
  for (int j = 0; j < 4; j++) b0[j] = *(const bf16x8*)Bb[j];

#pragma unroll
  for (int kk = 0; kk < VEC_ / 32; kk++) {
    const int kn = kk * 32 + 32;
    if (kn < VEC_) {  // prefetch next K-slice (compile-time folded on tail)
#pragma unroll
      for (int i = 0; i < 4; i++) {
        na0[i] = *(const float4*)(Ab[i] + kn);
        na1[i] = *(const float4*)(Ab[i] + kn + 4);
      }
#pragma unroll
      for (int j = 0; j < 4; j++) nb0[j] = *(const bf16x8*)(Bb[j] + kn);
    }
    bf16x8 af[4];
#pragma unroll
    for (int i = 0; i < 4; i++)
      af[i] = (bf16x8){ (__bf16)a0[i].x, (__bf16)a0[i].y, (__bf16)a0[i].z, (__bf16)a0[i].w,
                        (__bf16)a1[i].x, (__bf16)a1[i].y, (__bf16)a1[i].z, (__bf16)a1[i].w };
#pragma unroll
    for (int i = 0; i < 4; i++)
#pragma unroll
      for (int j = 0; j < 4; j++)
        acc[i][j] = __builtin_amdgcn_mfma_f32_16x16x32_bf16(af[i], b0[j], acc[i][j], 0, 0, 0);
    // rotate (free after full unroll: SSA renaming)
#pragma unroll
    for (int i = 0; i < 4; i++) { a0[i] = na0[i]; a1[i] = na1[i]; }
#pragma unroll
    for (int j = 0; j < 4; j++) b0[j] = nb0[j];
  }

  // epilogue: bias + relu, store bf16 (tensor 0), column sums -> atomicAdd doc sums
#pragma unroll
  for (int j = 0; j < 4; j++) {
    const int n = n0 + wn + j * 16 + c;
    const float bias = mlp_b[n];
    float colsum = 0.f;
#pragma unroll
    for (int i = 0; i < 4; i++) {
      const int mbase = m0 + wm + i * 16 + q * 4;
#pragma unroll
      for (int r = 0; r < 4; r++) {
        float v = acc[i][j][r] + bias;
        v = fmaxf(v, 0.f);
        colsum += v;
        if (tensor == 0) o1[(size_t)(mbase + r) * H_ + n] = (__bf16)v;
      }
    }
    colsum += __shfl_down(colsum, 32);
    colsum += __shfl_down(colsum, 16);
    if (lane < 16)
      atomicAdd(&dsum[bidx * H_ + n0 + wn + j * 16 + lane], colsum);
  }
}

// logits[b,s] = o1[b,s,:] . o2_doc[b,:]  (s<512);  logits[b,512] = o1_doc . o2_doc
__global__ __launch_bounds__(256) void logits_kernel(
    const __bf16* __restrict__ o1, const float* __restrict__ sum1,
    const float* __restrict__ sum2, float* __restrict__ lg)
{
  const int b = blockIdx.y;
  const int schunk = blockIdx.x;  // 0..7, 64 s-rows each
  const int t = threadIdx.x, lane = t & 63, wave = t >> 6;
  __shared__ __align__(16) float o2d[256];
  if (t < 256) o2d[t] = sum2[b * H_ + t] * (1.f / 512.f);
  __syncthreads();
  const float4 w = ((const float4*)o2d)[lane];
  const int sbase = schunk * 64;
  for (int s = sbase + wave; s < sbase + 64; s += 4) {
    const bf16x4 x = *(const bf16x4*)&o1[((size_t)b * S_ + s) * H_ + lane * 4];
    float p = (float)x[0] * w.x + (float)x[1] * w.y + (float)x[2] * w.z + (float)x[3] * w.w;
    p += __shfl_down(p, 32); p += __shfl_down(p, 16); p += __shfl_down(p, 8);
    p += __shfl_down(p, 4);  p += __shfl_down(p, 2);  p += __shfl_down(p, 1);
    if (lane == 0) lg[b * 513 + s] = p;
  }
  if (schunk == 0 && wave == 0) {
    const float4 x = ((const float4*)&sum1[b * H_])[lane];
    float p = (x.x * w.x + x.y * w.y + x.z * w.z + x.w * w.w) * (1.f / 512.f);
    p += __shfl_down(p, 32); p += __shfl_down(p, 16); p += __shfl_down(p, 8);
    p += __shfl_down(p, 4);  p += __shfl_down(p, 2);  p += __shfl_down(p, 1);
    if (lane == 0) lg[b * 513 + 512] = p;
  }
}

// fused: MLP head (row 512 of att) + softmax over 513 logits (rows 0..511)
__global__ __launch_bounds__(256) void softmax_head_kernel(
    const float* __restrict__ lg, const float* __restrict__ sum1, const float* __restrict__ sum2,
    const float* __restrict__ fd_w, const float* __restrict__ fd_b,
    const float* __restrict__ ff_w, const float* __restrict__ ff_b,
    float* __restrict__ out)
{
  const int b = blockIdx.x, t = threadIdx.x, lane = t & 63, wave = t >> 6;
  __shared__ __align__(16) float dc[512];
  __shared__ float sl[513];
  __shared__ float red[4], r1[4], r2[4];

  // --- head: h = relu(fd_w @ cat(o1_doc,o2_doc) + fd_b); out[512,b] = sigmoid(ff_w.h + ff_b)
  dc[t]       = sum1[b * H_ + t] * (1.f / 512.f);
  dc[t + 256] = sum2[b * H_ + t] * (1.f / 512.f);
  for (int i = t; i < 513; i += 256) sl[i] = lg[b * 513 + i];
  __syncthreads();
  const float4* wrow = (const float4*)&fd_w[(size_t)t * 512];
  const float4* dc4  = (const float4*)dc;
  float acc = 0.f;
  for (int k = 0; k < 128; k++) {
    const float4 w = wrow[k], d = dc4[k];
    acc += w.x * d.x + w.y * d.y + w.z * d.z + w.w * d.w;
  }
  const float h = fmaxf(acc + fd_b[t], 0.f);
  float part = ff_w[t] * h;
  part += __shfl_down(part, 32); part += __shfl_down(part, 16);
  part += __shfl_down(part, 8);  part += __shfl_down(part, 4);
  part += __shfl_down(part, 2);  part += __shfl_down(part, 1);
  if (lane == 0) red[wave] = part;

  // --- softmax over sl[0..512]
  float m = -1e30f;
  for (int i = t; i < 513; i += 256) m = fmaxf(m, sl[i]);
  m = fmaxf(m, __shfl_down(m, 32)); m = fmaxf(m, __shfl_down(m, 16));
  m = fmaxf(m, __shfl_down(m, 8));  m = fmaxf(m, __shfl_down(m, 4));
  m = fmaxf(m, __shfl_down(m, 2));  m = fmaxf(m, __shfl_down(m, 1));
  if (lane == 0) r1[wave] = m;
  __syncthreads();
  m = fmaxf(fmaxf(r1[0], r1[1]), fmaxf(r1[2], r1[3]));
  float psum = 0.f;
  for (int i = t; i < 513; i += 256) { const float e = expf(sl[i] - m); sl[i] = e; psum += e; }
  psum += __shfl_down(psum, 32); psum += __shfl_down(psum, 16); psum += __shfl_down(psum, 8);
  psum += __shfl_down(psum, 4);  psum += __shfl_down(psum, 2);  psum += __shfl_down(psum, 1);
  if (lane == 0) r2[wave] = psum;
  __syncthreads();
  const float inv = 1.f / (r2[0] + r2[1] + r2[2] + r2[3]);
  for (int s = t; s < 512; s += 256) out[s * 64 + b] = sl[s] * inv;
  if (t == 0) {
    const float tot = red[0] + red[1] + red[2] + red[3] + ff_b[0];
    out[(size_t)512 * 64 + b] = 1.f / (1.f + expf(-tot));
  }
}

extern "C" void kernel_launch(void* const* d_in, const int* in_sizes, int n_in,
                              void* d_out, int out_size, void* d_ws, size_t ws_size,
                              hipStream_t stream) {
  const float* out1  = (const float*)d_in[0];
  const float* out2  = (const float*)d_in[1];
  const float* mlp_w = (const float*)d_in[2];
  const float* mlp_b = (const float*)d_in[3];
  const float* fd_w  = (const float*)d_in[4];
  const float* fd_b  = (const float*)d_in[5];
  const float* ff_w  = (const float*)d_in[6];
  const float* ff_b  = (const float*)d_in[7];
  float* out = (float*)d_out;

  __bf16* o1  = (__bf16*)d_ws;                       // 32768*256 bf16 = 16.78 MB
  __bf16* wbf = o1 + (size_t)M_ * H_;                // 256*768 bf16
  float*  s1  = (float*)(wbf + (size_t)H_ * VEC_);   // 64*256 f32
  float*  s2  = s1 + B_ * H_;                        // 64*256 f32
  float*  lgw = s2 + B_ * H_;                        // 64*513 f32

  prep_kernel<<<224, 256, 0, stream>>>(mlp_w, wbf, s1);
  gemm_doc_kernel<<<dim3(2, 256, 2), 256, 0, stream>>>(out1, out2, wbf, mlp_b, o1, s1, s2);
  logits_kernel<<<dim3(8, B_), 256, 0, stream>>>(o1, s1, s2, lgw);
  softmax_head_kernel<<<B_, 256, 0, stream>>>(lgw, s1, s2, fd_w, fd_b, ff_w, ff_b, out);
}

// Round 4
// 331.549 us; speedup vs baseline: 1.2109x; 1.2109x over previous
//
#include <hip/hip_runtime.h>
#include <hip/hip_bf16.h>
#include <math.h>

#define B_ 64
#define S_ 512
#define VEC_ 768
#define H_ 256
#define M_ (B_*S_)   // 32768

typedef float floatx4 __attribute__((ext_vector_type(4)));
typedef __bf16 bf16x8 __attribute__((ext_vector_type(8)));
typedef __bf16 bf16x4 __attribute__((ext_vector_type(4)));

#define STRIDE 40  // LDS row stride in bf16: 80 B, 16-B aligned b128 reads, 2-way banks (free)

// prep: cast mlp_w (f32 [256,768]) -> bf16, zero doc-sum accumulators
__global__ __launch_bounds__(256) void prep_kernel(
    const float* __restrict__ mlp_w, __bf16* __restrict__ wbf, float* __restrict__ sums)
{
  const int bid = blockIdx.x;
  if (bid < 192) {
    const int i = bid * 256 + threadIdx.x;           // float4 index, 49152 total
    const float4 v = ((const float4*)mlp_w)[i];
    bf16x4 b = { (__bf16)v.x, (__bf16)v.y, (__bf16)v.z, (__bf16)v.w };
    *(bf16x4*)&wbf[(size_t)i * 4] = b;
  } else {
    const int i = (bid - 192) * 256 + threadIdx.x;   // 8192 float4 = 2*64*256 f32
    ((float4*)sums)[i] = make_float4(0.f, 0.f, 0.f, 0.f);
  }
}

// GEMM: C[m,n] = relu(sum_k A[m,k]*W[n,k] + mlp_b[n]); A = output_1/output_2 per blockIdx.z.
// LDS-staged MFMA with DISTANCE-2 register prefetch: two named register buffers,
// manually 2-step-unrolled K loop so the pipeline survives regalloc. Plain VGPR
// global loads are NOT drained at __syncthreads, so loads issued at iter k are
// first waited on at the LDS stores of iter k+2 (~2 full iterations of slack).
__global__ __launch_bounds__(256, 3) void gemm_doc_kernel(
    const float* __restrict__ out1, const float* __restrict__ out2,
    const __bf16* __restrict__ wbf, const float* __restrict__ mlp_b,
    __bf16* __restrict__ o1, float* __restrict__ sum1, float* __restrict__ sum2)
{
  __shared__ __align__(16) __bf16 As[128 * STRIDE];
  __shared__ __align__(16) __bf16 Bs[128 * STRIDE];

  const int tensor = blockIdx.z;
  const float* __restrict__ A = tensor ? out2 : out1;
  float* __restrict__ dsum = tensor ? sum2 : sum1;

  const int n0 = blockIdx.x * 128;
  const int m0 = blockIdx.y * 128;
  const int bidx = m0 >> 9;  // 512 rows per doc; m-tiles never straddle docs

  const int t = threadIdx.x;
  const int lane = t & 63;
  const int wave = t >> 6;
  const int q = lane >> 4;
  const int c = lane & 15;
  const int wm = (wave >> 1) * 64;
  const int wn = (wave & 1) * 64;

  floatx4 acc[4][4];
#pragma unroll
  for (int i = 0; i < 4; i++)
#pragma unroll
    for (int j = 0; j < 4; j++)
      acc[i][j] = (floatx4){0.f, 0.f, 0.f, 0.f};

  // Staging ownership (per 128x32 tile):
  //   A: 1024 float4 chunks; thread t owns ch = t + i*256, row=ch>>3, col4=(ch&7)*4
  //   B: 512 bf16x8 chunks;  thread t owns ch = t + i*256 (i<2), row=ch>>2, col8=(ch&3)*8
  const float*  Abase = &A[(size_t)m0 * VEC_];
  const __bf16* Wbase = &wbf[(size_t)n0 * VEC_];
  const int arow[4] = { (t + 0) >> 3, (t + 256) >> 3, (t + 512) >> 3, (t + 768) >> 3 };
  const int acol = (t & 7) * 4;
  const int brow[2] = { (t + 0) >> 2, (t + 256) >> 2 };
  const int bcol = (t & 3) * 8;

  float4 a0[4], a1[4];   // buffer 0 / buffer 1 (A)
  bf16x8 b0[2], b1[2];   // buffer 0 / buffer 1 (B)

  auto loadA = [&](float4 (&buf)[4], int k0) {
#pragma unroll
    for (int i = 0; i < 4; i++)
      buf[i] = *(const float4*)&Abase[(size_t)arow[i] * VEC_ + k0 + acol];
  };
  auto loadB = [&](bf16x8 (&buf)[2], int k0) {
#pragma unroll
    for (int i = 0; i < 2; i++)
      buf[i] = *(const bf16x8*)&Wbase[(size_t)brow[i] * VEC_ + k0 + bcol];
  };
  auto compute = [&]() {
    bf16x8 af[4], bfr[4];
#pragma unroll
    for (int i = 0; i < 4; i++) af[i]  = *(const bf16x8*)&As[(wm + i * 16 + c) * STRIDE + q * 8];
#pragma unroll
    for (int j = 0; j < 4; j++) bfr[j] = *(const bf16x8*)&Bs[(wn + j * 16 + c) * STRIDE + q * 8];
#pragma unroll
    for (int i = 0; i < 4; i++)
#pragma unroll
      for (int j = 0; j < 4; j++)
        acc[i][j] = __builtin_amdgcn_mfma_f32_16x16x32_bf16(af[i], bfr[j], acc[i][j], 0, 0, 0);
  };
  auto step = [&](float4 (&ab)[4], bf16x8 (&bb)[2], int kpre) {
    // store current buffer to LDS (vmcnt wait here targets loads issued 2 iters ago)
#pragma unroll
    for (int i = 0; i < 4; i++) {
      bf16x4 v = { (__bf16)ab[i].x, (__bf16)ab[i].y, (__bf16)ab[i].z, (__bf16)ab[i].w };
      *(bf16x4*)&As[arow[i] * STRIDE + acol] = v;
    }
#pragma unroll
    for (int i = 0; i < 2; i++)
      *(bf16x8*)&Bs[brow[i] * STRIDE + bcol] = bb[i];
    // refill same buffer with tile kpre (consumed 2 iterations later)
    if (kpre < VEC_) { loadA(ab, kpre); loadB(bb, kpre); }
    __syncthreads();
    compute();
    __syncthreads();
  };

  // prologue: fill both buffers
  loadA(a0, 0);  loadB(b0, 0);
  loadA(a1, 32); loadB(b1, 32);

#pragma unroll 1
  for (int kk = 0; kk < VEC_ / 32; kk += 2) {
    step(a0, b0, kk * 32 + 64);
    step(a1, b1, kk * 32 + 96);
  }

  // epilogue: bias + relu, store bf16 (tensor 0), column sums -> atomicAdd doc sums
#pragma unroll
  for (int j = 0; j < 4; j++) {
    const int n = n0 + wn + j * 16 + c;
    const float bias = mlp_b[n];
    float colsum = 0.f;
#pragma unroll
    for (int i = 0; i < 4; i++) {
      const int mbase = m0 + wm + i * 16 + q * 4;
#pragma unroll
      for (int r = 0; r < 4; r++) {
        float v = acc[i][j][r] + bias;
        v = fmaxf(v, 0.f);
        colsum += v;
        if (tensor == 0) o1[(size_t)(mbase + r) * H_ + n] = (__bf16)v;
      }
    }
    colsum += __shfl_down(colsum, 32);
    colsum += __shfl_down(colsum, 16);
    if (lane < 16)
      atomicAdd(&dsum[bidx * H_ + n0 + wn + j * 16 + lane], colsum);
  }
}

// logits[b,s] = o1[b,s,:] . o2_doc[b,:]  (s<512);  logits[b,512] = o1_doc . o2_doc
__global__ __launch_bounds__(256) void logits_kernel(
    const __bf16* __restrict__ o1, const float* __restrict__ sum1,
    const float* __restrict__ sum2, float* __restrict__ lg)
{
  const int b = blockIdx.y;
  const int schunk = blockIdx.x;  // 0..7, 64 s-rows each
  const int t = threadIdx.x, lane = t & 63, wave = t >> 6;
  __shared__ __align__(16) float o2d[256];
  if (t < 256) o2d[t] = sum2[b * H_ + t] * (1.f / 512.f);
  __syncthreads();
  const float4 w = ((const float4*)o2d)[lane];
  const int sbase = schunk * 64;
  for (int s = sbase + wave; s < sbase + 64; s += 4) {
    const bf16x4 x = *(const bf16x4*)&o1[((size_t)b * S_ + s) * H_ + lane * 4];
    float p = (float)x[0] * w.x + (float)x[1] * w.y + (float)x[2] * w.z + (float)x[3] * w.w;
    p += __shfl_down(p, 32); p += __shfl_down(p, 16); p += __shfl_down(p, 8);
    p += __shfl_down(p, 4);  p += __shfl_down(p, 2);  p += __shfl_down(p, 1);
    if (lane == 0) lg[b * 513 + s] = p;
  }
  if (schunk == 0 && wave == 0) {
    const float4 x = ((const float4*)&sum1[b * H_])[lane];
    float p = (x.x * w.x + x.y * w.y + x.z * w.z + x.w * w.w) * (1.f / 512.f);
    p += __shfl_down(p, 32); p += __shfl_down(p, 16); p += __shfl_down(p, 8);
    p += __shfl_down(p, 4);  p += __shfl_down(p, 2);  p += __shfl_down(p, 1);
    if (lane == 0) lg[b * 513 + 512] = p;
  }
}

// fused: MLP head (row 512 of att) + softmax over 513 logits (rows 0..511)
__global__ __launch_bounds__(256) void softmax_head_kernel(
    const float* __restrict__ lg, const float* __restrict__ sum1, const float* __restrict__ sum2,
    const float* __restrict__ fd_w, const float* __restrict__ fd_b,
    const float* __restrict__ ff_w, const float* __restrict__ ff_b,
    float* __restrict__ out)
{
  const int b = blockIdx.x, t = threadIdx.x, lane = t & 63, wave = t >> 6;
  __shared__ __align__(16) float dc[512];
  __shared__ float sl[513];
  __shared__ float red[4], r1[4], r2[4];

  // --- head: h = relu(fd_w @ cat(o1_doc,o2_doc) + fd_b); out[512,b] = sigmoid(ff_w.h + ff_b)
  dc[t]       = sum1[b * H_ + t] * (1.f / 512.f);
  dc[t + 256] = sum2[b * H_ + t] * (1.f / 512.f);
  for (int i = t; i < 513; i += 256) sl[i] = lg[b * 513 + i];
  __syncthreads();
  const float4* wrow = (const float4*)&fd_w[(size_t)t * 512];
  const float4* dc4  = (const float4*)dc;
  float acc = 0.f;
  for (int k = 0; k < 128; k++) {
    const float4 w = wrow[k], d = dc4[k];
    acc += w.x * d.x + w.y * d.y + w.z * d.z + w.w * d.w;
  }
  const float h = fmaxf(acc + fd_b[t], 0.f);
  float part = ff_w[t] * h;
  part += __shfl_down(part, 32); part += __shfl_down(part, 16);
  part += __shfl_down(part, 8);  part += __shfl_down(part, 4);
  part += __shfl_down(part, 2);  part += __shfl_down(part, 1);
  if (lane == 0) red[wave] = part;

  // --- softmax over sl[0..512]
  float m = -1e30f;
  for (int i = t; i < 513; i += 256) m = fmaxf(m, sl[i]);
  m = fmaxf(m, __shfl_down(m, 32)); m = fmaxf(m, __shfl_down(m, 16));
  m = fmaxf(m, __shfl_down(m, 8));  m = fmaxf(m, __shfl_down(m, 4));
  m = fmaxf(m, __shfl_down(m, 2));  m = fmaxf(m, __shfl_down(m, 1));
  if (lane == 0) r1[wave] = m;
  __syncthreads();
  m = fmaxf(fmaxf(r1[0], r1[1]), fmaxf(r1[2], r1[3]));
  float psum = 0.f;
  for (int i = t; i < 513; i += 256) { const float e = expf(sl[i] - m); sl[i] = e; psum += e; }
  psum += __shfl_down(psum, 32); psum += __shfl_down(psum, 16); psum += __shfl_down(psum, 8);
  psum += __shfl_down(psum, 4);  psum += __shfl_down(psum, 2);  psum += __shfl_down(psum, 1);
  if (lane == 0) r2[wave] = psum;
  __syncthreads();
  const float inv = 1.f / (r2[0] + r2[1] + r2[2] + r2[3]);
  for (int s = t; s < 512; s += 256) out[s * 64 + b] = sl[s] * inv;
  if (t == 0) {
    const float tot = red[0] + red[1] + red[2] + red[3] + ff_b[0];
    out[(size_t)512 * 64 + b] = 1.f / (1.f + expf(-tot));
  }
}

extern "C" void kernel_launch(void* const* d_in, const int* in_sizes, int n_in,
                              void* d_out, int out_size, void* d_ws, size_t ws_size,
                              hipStream_t stream) {
  const float* out1  = (const float*)d_in[0];
  const float* out2  = (const float*)d_in[1];
  const float* mlp_w = (const float*)d_in[2];
  const float* mlp_b = (const float*)d_in[3];
  const float* fd_w  = (const float*)d_in[4];
  const float* fd_b  = (const float*)d_in[5];
  const float* ff_w  = (const float*)d_in[6];
  const float* ff_b  = (const float*)d_in[7];
  float* out = (float*)d_out;

  __bf16* o1  = (__bf16*)d_ws;                       // 32768*256 bf16 = 16.78 MB
  __bf16* wbf = o1 + (size_t)M_ * H_;                // 256*768 bf16
  float*  s1  = (float*)(wbf + (size_t)H_ * VEC_);   // 64*256 f32
  float*  s2  = s1 + B_ * H_;                        // 64*256 f32
  float*  lgw = s2 + B_ * H_;                        // 64*513 f32

  prep_kernel<<<224, 256, 0, stream>>>(mlp_w, wbf, s1);
  gemm_doc_kernel<<<dim3(2, 256, 2), 256, 0, stream>>>(out1, out2, wbf, mlp_b, o1, s1, s2);
  logits_kernel<<<dim3(8, B_), 256, 0, stream>>>(o1, s1, s2, lgw);
  softmax_head_kernel<<<B_, 256, 0, stream>>>(lgw, s1, s2, fd_w, fd_b, ff_w, ff_b, out);
}

// Round 5
// 292.055 us; speedup vs baseline: 1.3747x; 1.1352x over previous
//
#include <hip/hip_runtime.h>
#include <hip/hip_bf16.h>
#include <math.h>

#define B_ 64
#define S_ 512
#define VEC_ 768
#define H_ 256
#define M_ (B_*S_)   // 32768

typedef float floatx4 __attribute__((ext_vector_type(4)));
typedef __bf16 bf16x8 __attribute__((ext_vector_type(8)));
typedef __bf16 bf16x4 __attribute__((ext_vector_type(4)));

// async global->LDS DMA, 16 B per lane; LDS dest = wave-uniform base + lane*16
__device__ __forceinline__ void gl_lds16(const void* g, void* l) {
  __builtin_amdgcn_global_load_lds(
      (const __attribute__((address_space(1))) void*)g,
      (__attribute__((address_space(3))) void*)l, 16, 0, 0);
}

// prep: cast mlp_w (f32 [256,768]) -> bf16, zero doc-sum accumulators
__global__ __launch_bounds__(256) void prep_kernel(
    const float* __restrict__ mlp_w, __bf16* __restrict__ wbf, float* __restrict__ sums)
{
  const int bid = blockIdx.x;
  if (bid < 192) {
    const int i = bid * 256 + threadIdx.x;           // float4 index, 49152 total
    const float4 v = ((const float4*)mlp_w)[i];
    bf16x4 b = { (__bf16)v.x, (__bf16)v.y, (__bf16)v.z, (__bf16)v.w };
    *(bf16x4*)&wbf[(size_t)i * 4] = b;
  } else {
    const int i = (bid - 192) * 256 + threadIdx.x;   // 8192 float4 = 2*64*256 f32
    ((float4*)sums)[i] = make_float4(0.f, 0.f, 0.f, 0.f);
  }
}

// GEMM: C[m,n] = relu(sum_k A[m,k]*W[n,k] + mlp_b[n]); A = output_1/output_2 per blockIdx.z.
// m97 structure: global_load_lds DMA staging (A as f32, XOR-swizzled 16B chunks so
// unpadded fragment reads are bank-uniform; B pre-cast bf16, naturally uniform),
// f32->bf16 conversion at fragment-read time. No staging VGPRs -> nothing to spill.
__global__ __launch_bounds__(256, 4) void gemm_doc_kernel(
    const float* __restrict__ out1, const float* __restrict__ out2,
    const __bf16* __restrict__ wbf, const float* __restrict__ mlp_b,
    __bf16* __restrict__ o1, float* __restrict__ sum1, float* __restrict__ sum2)
{
  __shared__ __align__(16) float  As[128 * 32];   // 16 KB, chunk (row,pos) holds global chunk pos^(row&7)
  __shared__ __align__(16) __bf16 Bs[128 * 32];   // 8 KB, row-major

  const int tensor = blockIdx.z;
  const float* __restrict__ A = tensor ? out2 : out1;
  float* __restrict__ dsum = tensor ? sum2 : sum1;

  const int n0 = blockIdx.x * 128;
  const int m0 = blockIdx.y * 128;
  const int bidx = m0 >> 9;  // 512 rows per doc; m-tiles never straddle docs

  const int t = threadIdx.x;
  const int lane = t & 63;
  const int wave = t >> 6;
  const int q = lane >> 4;
  const int c = lane & 15;
  const int wm = (wave >> 1) * 64;
  const int wn = (wave & 1) * 64;

  // A staging: slot s = wave*256 + j*64 + lane (16B slots); row = s>>3, pos = s&7,
  // global chunk = pos ^ (row&7)  (swizzled gather -> swizzled LDS residency)
  int arow[4], agch[4];
#pragma unroll
  for (int j = 0; j < 4; j++) {
    const int s = wave * 256 + j * 64 + lane;
    arow[j] = s >> 3;
    agch[j] = (s & 7) ^ (arow[j] & 7);
  }
  // B staging: slot s = wave*128 + j*64 + lane; row = s>>2, chunk = s&3 (no swizzle)
  int brow[2], bch[2];
#pragma unroll
  for (int j = 0; j < 2; j++) {
    const int s = wave * 128 + j * 64 + lane;
    brow[j] = s >> 2;
    bch[j] = s & 3;
  }

  floatx4 acc[4][4];
#pragma unroll
  for (int i = 0; i < 4; i++)
#pragma unroll
    for (int j = 0; j < 4; j++)
      acc[i][j] = (floatx4){0.f, 0.f, 0.f, 0.f};

#pragma unroll 1
  for (int k0 = 0; k0 < VEC_; k0 += 32) {
    // DMA-stage tile k0 (6 instrs/wave, 16 B/lane each)
#pragma unroll
    for (int j = 0; j < 4; j++)
      gl_lds16(&A[(size_t)(m0 + arow[j]) * VEC_ + k0 + agch[j] * 4],
               &As[(wave * 256 + j * 64) * 4]);
#pragma unroll
    for (int j = 0; j < 2; j++)
      gl_lds16(&wbf[(size_t)(n0 + brow[j]) * VEC_ + k0 + bch[j] * 8],
               &Bs[(wave * 128 + j * 64) * 8]);
    __syncthreads();  // drains vmcnt -> LDS tile complete for all waves

    bf16x8 af[4], bfr[4];
#pragma unroll
    for (int i = 0; i < 4; i++) {
      const int r = wm + i * 16 + c;
      const int p0 = (2 * q) ^ (r & 7);          // LDS pos of global chunk 2q (k=8q..8q+3)
      const floatx4 lo = *(const floatx4*)&As[r * 32 + p0 * 4];
      const floatx4 hi = *(const floatx4*)&As[r * 32 + (p0 ^ 1) * 4];
      af[i] = (bf16x8){ (__bf16)lo[0], (__bf16)lo[1], (__bf16)lo[2], (__bf16)lo[3],
                        (__bf16)hi[0], (__bf16)hi[1], (__bf16)hi[2], (__bf16)hi[3] };
    }
#pragma unroll
    for (int j = 0; j < 4; j++)
      bfr[j] = *(const bf16x8*)&Bs[(wn + j * 16 + c) * 32 + q * 8];
#pragma unroll
    for (int i = 0; i < 4; i++)
#pragma unroll
      for (int j = 0; j < 4; j++)
        acc[i][j] = __builtin_amdgcn_mfma_f32_16x16x32_bf16(af[i], bfr[j], acc[i][j], 0, 0, 0);
    __syncthreads();  // all waves done reading before next tile's DMA overwrites
  }

  // epilogue: bias + relu, store bf16 (tensor 0), column sums -> atomicAdd doc sums
#pragma unroll
  for (int j = 0; j < 4; j++) {
    const int n = n0 + wn + j * 16 + c;
    const float bias = mlp_b[n];
    float colsum = 0.f;
#pragma unroll
    for (int i = 0; i < 4; i++) {
      const int mbase = m0 + wm + i * 16 + q * 4;
#pragma unroll
      for (int r = 0; r < 4; r++) {
        float v = acc[i][j][r] + bias;
        v = fmaxf(v, 0.f);
        colsum += v;
        if (tensor == 0) o1[(size_t)(mbase + r) * H_ + n] = (__bf16)v;
      }
    }
    colsum += __shfl_down(colsum, 32);
    colsum += __shfl_down(colsum, 16);
    if (lane < 16)
      atomicAdd(&dsum[bidx * H_ + n0 + wn + j * 16 + lane], colsum);
  }
}

// logits[b,s] = o1[b,s,:] . o2_doc[b,:]  (s<512);  logits[b,512] = o1_doc . o2_doc
__global__ __launch_bounds__(256) void logits_kernel(
    const __bf16* __restrict__ o1, const float* __restrict__ sum1,
    const float* __restrict__ sum2, float* __restrict__ lg)
{
  const int b = blockIdx.y;
  const int schunk = blockIdx.x;  // 0..7, 64 s-rows each
  const int t = threadIdx.x, lane = t & 63, wave = t >> 6;
  __shared__ __align__(16) float o2d[256];
  if (t < 256) o2d[t] = sum2[b * H_ + t] * (1.f / 512.f);
  __syncthreads();
  const float4 w = ((const float4*)o2d)[lane];
  const int sbase = schunk * 64;
  for (int s = sbase + wave; s < sbase + 64; s += 4) {
    const bf16x4 x = *(const bf16x4*)&o1[((size_t)b * S_ + s) * H_ + lane * 4];
    float p = (float)x[0] * w.x + (float)x[1] * w.y + (float)x[2] * w.z + (float)x[3] * w.w;
    p += __shfl_down(p, 32); p += __shfl_down(p, 16); p += __shfl_down(p, 8);
    p += __shfl_down(p, 4);  p += __shfl_down(p, 2);  p += __shfl_down(p, 1);
    if (lane == 0) lg[b * 513 + s] = p;
  }
  if (schunk == 0 && wave == 0) {
    const float4 x = ((const float4*)&sum1[b * H_])[lane];
    float p = (x.x * w.x + x.y * w.y + x.z * w.z + x.w * w.w) * (1.f / 512.f);
    p += __shfl_down(p, 32); p += __shfl_down(p, 16); p += __shfl_down(p, 8);
    p += __shfl_down(p, 4);  p += __shfl_down(p, 2);  p += __shfl_down(p, 1);
    if (lane == 0) lg[b * 513 + 512] = p;
  }
}

// fused: MLP head (row 512 of att) + softmax over 513 logits (rows 0..511)
__global__ __launch_bounds__(256) void softmax_head_kernel(
    const float* __restrict__ lg, const float* __restrict__ sum1, const float* __restrict__ sum2,
    const float* __restrict__ fd_w, const float* __restrict__ fd_b,
    const float* __restrict__ ff_w, const float* __restrict__ ff_b,
    float* __restrict__ out)
{
  const int b = blockIdx.x, t = threadIdx.x, lane = t & 63, wave = t >> 6;
  __shared__ __align__(16) float dc[512];
  __shared__ float sl[513];
  __shared__ float red[4], r1[4], r2[4];

  // --- head: h = relu(fd_w @ cat(o1_doc,o2_doc) + fd_b); out[512,b] = sigmoid(ff_w.h + ff_b)
  dc[t]       = sum1[b * H_ + t] * (1.f / 512.f);
  dc[t + 256] = sum2[b * H_ + t] * (1.f / 512.f);
  for (int i = t; i < 513; i += 256) sl[i] = lg[b * 513 + i];
  __syncthreads();
  const float4* wrow = (const float4*)&fd_w[(size_t)t * 512];
  const float4* dc4  = (const float4*)dc;
  float acc = 0.f;
  for (int k = 0; k < 128; k++) {
    const float4 w = wrow[k], d = dc4[k];
    acc += w.x * d.x + w.y * d.y + w.z * d.z + w.w * d.w;
  }
  const float h = fmaxf(acc + fd_b[t], 0.f);
  float part = ff_w[t] * h;
  part += __shfl_down(part, 32); part += __shfl_down(part, 16);
  part += __shfl_down(part, 8);  part += __shfl_down(part, 4);
  part += __shfl_down(part, 2);  part += __shfl_down(part, 1);
  if (lane == 0) red[wave] = part;

  // --- softmax over sl[0..512]
  float m = -1e30f;
  for (int i = t; i < 513; i += 256) m = fmaxf(m, sl[i]);
  m = fmaxf(m, __shfl_down(m, 32)); m = fmaxf(m, __shfl_down(m, 16));
  m = fmaxf(m, __shfl_down(m, 8));  m = fmaxf(m, __shfl_down(m, 4));
  m = fmaxf(m, __shfl_down(m, 2));  m = fmaxf(m, __shfl_down(m, 1));
  if (lane == 0) r1[wave] = m;
  __syncthreads();
  m = fmaxf(fmaxf(r1[0], r1[1]), fmaxf(r1[2], r1[3]));
  float psum = 0.f;
  for (int i = t; i < 513; i += 256) { const float e = expf(sl[i] - m); sl[i] = e; psum += e; }
  psum += __shfl_down(psum, 32); psum += __shfl_down(psum, 16); psum += __shfl_down(psum, 8);
  psum += __shfl_down(psum, 4);  psum += __shfl_down(psum, 2);  psum += __shfl_down(psum, 1);
  if (lane == 0) r2[wave] = psum;
  __syncthreads();
  const float inv = 1.f / (r2[0] + r2[1] + r2[2] + r2[3]);
  for (int s = t; s < 512; s += 256) out[s * 64 + b] = sl[s] * inv;
  if (t == 0) {
    const float tot = red[0] + red[1] + red[2] + red[3] + ff_b[0];
    out[(size_t)512 * 64 + b] = 1.f / (1.f + expf(-tot));
  }
}

extern "C" void kernel_launch(void* const* d_in, const int* in_sizes, int n_in,
                              void* d_out, int out_size, void* d_ws, size_t ws_size,
                              hipStream_t stream) {
  const float* out1  = (const float*)d_in[0];
  const float* out2  = (const float*)d_in[1];
  const float* mlp_w = (const float*)d_in[2];
  const float* mlp_b = (const float*)d_in[3];
  const float* fd_w  = (const float*)d_in[4];
  const float* fd_b  = (const float*)d_in[5];
  const float* ff_w  = (const float*)d_in[6];
  const float* ff_b  = (const float*)d_in[7];
  float* out = (float*)d_out;

  __bf16* o1  = (__bf16*)d_ws;                       // 32768*256 bf16 = 16.78 MB
  __bf16* wbf = o1 + (size_t)M_ * H_;                // 256*768 bf16
  float*  s1  = (float*)(wbf + (size_t)H_ * VEC_);   // 64*256 f32
  float*  s2  = s1 + B_ * H_;                        // 64*256 f32
  float*  lgw = s2 + B_ * H_;                        // 64*513 f32

  prep_kernel<<<224, 256, 0, stream>>>(mlp_w, wbf, s1);
  gemm_doc_kernel<<<dim3(2, 256, 2), 256, 0, stream>>>(out1, out2, wbf, mlp_b, o1, s1, s2);
  logits_kernel<<<dim3(8, B_), 256, 0, stream>>>(o1, s1, s2, lgw);
  softmax_head_kernel<<<B_, 256, 0, stream>>>(lgw, s1, s2, fd_w, fd_b, ff_w, ff_b, out);
}